// Round 1
// baseline (949.171 us; speedup 1.0000x reference)
//
#include <hip/hip_runtime.h>
#include <float.h>

#define L_TOK 65536
#define DIM   64
#define NCODE 1024

// ---------------------------------------------------------------------------
// Kernel A: per-code ||e||^2 (fp32). Order-insensitive at the 1e-12 level.
// ---------------------------------------------------------------------------
__global__ __launch_bounds__(256) void esum_kernel(const float* __restrict__ emb,
                                                   float* __restrict__ esum) {
    int n = blockIdx.x * 256 + threadIdx.x;
    if (n >= NCODE) return;
    const float* e = emb + ((size_t)n << 6);
    float s = 0.f;
#pragma unroll
    for (int k = 0; k < DIM; ++k) s = fmaf(e[k], e[k], s);
    esum[n] = s;
}

// ---------------------------------------------------------------------------
// Kernel B: argmin over codes.
// thread = (token, sub) with sub in {0,1} covering code ranges [0,512),[512,1024).
// z row held in 64 VGPRs; two independent sequential-k FMA chains per step
// (hides 4-cyc dependent-FMA latency); dist replicates the reference rounding:
//    d = fl( fl(zs + es[n]) - 2*acc )   (2*acc exact; FMA contraction identical)
// Tie-break: strict '<' scanning ascending n == first-index-wins (np.argmin).
// ---------------------------------------------------------------------------
__global__ __launch_bounds__(256) void argmin_kernel(const float* __restrict__ z,
                                                     const float* __restrict__ emb,
                                                     const float* __restrict__ esum,
                                                     float* __restrict__ idx_out) {
    int tid   = blockIdx.x * 256 + threadIdx.x;
    int token = tid >> 1;
    int sub   = tid & 1;

    const float* zr = z + ((size_t)token << 6);
    float zreg[DIM];
#pragma unroll
    for (int i = 0; i < 16; ++i) {
        float4 v = ((const float4*)zr)[i];
        zreg[4*i+0] = v.x; zreg[4*i+1] = v.y;
        zreg[4*i+2] = v.z; zreg[4*i+3] = v.w;
    }

    // zsum: any order is safe (uniform per-row shift preserves argmin ordering),
    // but both sub-lanes of a token compute it identically (same sequence).
    float zs = 0.f;
#pragma unroll
    for (int k = 0; k < DIM; ++k) zs = fmaf(zreg[k], zreg[k], zs);

    float best = FLT_MAX;
    int   bi   = 0;
    const int base = sub * 512;

    for (int j = 0; j < 256; ++j) {
        const int r0 = base + 2*j;
        const int r1 = r0 + 1;
        const float* e0 = emb + ((size_t)r0 << 6);
        const float* e1 = emb + ((size_t)r1 << 6);
        float a0 = 0.f, a1 = 0.f;
#pragma unroll
        for (int k = 0; k < DIM; ++k) {
            a0 = fmaf(zreg[k], e0[k], a0);   // sequential-k fp32 FMA chain
            a1 = fmaf(zreg[k], e1[k], a1);
        }
        float t0 = zs + esum[r0];
        float t1 = zs + esum[r1];
        float d0 = t0 - 2.0f * a0;
        float d1 = t1 - 2.0f * a1;
        if (d0 < best) { best = d0; bi = r0; }
        if (d1 < best) { best = d1; bi = r1; }
    }

    // Combine the two halves; on exact tie prefer the lower index (np.argmin).
    float ob = __shfl_xor(best, 1);
    int   oi = __shfl_xor(bi,   1);
    if (ob < best || (ob == best && oi < bi)) { best = ob; bi = oi; }

    if (sub == 0) idx_out[token] = (float)bi;
}

// ---------------------------------------------------------------------------
// Kernel C: z_q_st + per-block f64 loss partials. One wave == one token row:
// idx broadcast, all global accesses fully coalesced. Replicates
//   t = fl(z_q - z);  out = fl(z + t);  sq = fl(t*t)
// Deterministic fixed-order block reduction.
// ---------------------------------------------------------------------------
__global__ __launch_bounds__(256) void output_kernel(const float* __restrict__ z,
                                                     const float* __restrict__ emb,
                                                     const float* __restrict__ idx_f,
                                                     float* __restrict__ zq_out,
                                                     double* __restrict__ partials) {
    int gid = blockIdx.x * 256 + threadIdx.x;
    int l = gid >> 6;
    int k = gid & 63;
    int idx = (int)idx_f[l];

    float zv = z[gid];
    float ev = emb[(idx << 6) + k];
    float t    = ev - zv;       // z_q - z   (fp32)
    float outv = zv + t;        // straight-through value (fp32)
    zq_out[gid] = outv;

    float sq = t * t;           // fp32 square, then accumulate in f64

    __shared__ double red[256];
    red[threadIdx.x] = (double)sq;
    __syncthreads();
    for (int s = 128; s > 0; s >>= 1) {
        if (threadIdx.x < s) red[threadIdx.x] += red[threadIdx.x + s];
        __syncthreads();
    }
    if (threadIdx.x == 0) partials[blockIdx.x] = red[0];
}

// ---------------------------------------------------------------------------
// Kernel D: final deterministic reduction of 16384 partials -> loss scalar.
// loss = beta*mean + mean = 0.25*m + m, computed f64 then rounded to f32.
// ---------------------------------------------------------------------------
__global__ __launch_bounds__(256) void loss_kernel(const double* __restrict__ partials,
                                                   float* __restrict__ loss_out) {
    __shared__ double red[256];
    int t = threadIdx.x;
    double s = 0.0;
    for (int i = 0; i < 64; ++i) s += partials[t * 64 + i];  // fixed order
    red[t] = s;
    __syncthreads();
    for (int st = 128; st > 0; st >>= 1) {
        if (t < st) red[t] += red[t + st];
        __syncthreads();
    }
    if (t == 0) {
        double m  = red[0] / (double)(L_TOK * DIM);
        float  mf = (float)m;
        loss_out[0] = 0.25f * mf + mf;
    }
}

extern "C" void kernel_launch(void* const* d_in, const int* in_sizes, int n_in,
                              void* d_out, int out_size, void* d_ws, size_t ws_size,
                              hipStream_t stream) {
    const float* z   = (const float*)d_in[0];
    const float* emb = (const float*)d_in[1];

    float* out   = (float*)d_out;
    float* zq    = out;                 // [0, 4194304)
    float* loss  = out + 4194304;       // [4194304]
    float* idxf  = out + 4194305;       // [4194305, 4259841)

    float*  esum     = (float*)d_ws;                          // 1024 f32
    double* partials = (double*)((char*)d_ws + 8192);         // 16384 f64

    esum_kernel  <<<4,     256, 0, stream>>>(emb, esum);
    argmin_kernel<<<512,   256, 0, stream>>>(z, emb, esum, idxf);
    output_kernel<<<16384, 256, 0, stream>>>(z, emb, idxf, zq, partials);
    loss_kernel  <<<1,     256, 0, stream>>>(partials, loss);
}

// Round 2
// 184.802 us; speedup vs baseline: 5.1361x; 5.1361x over previous
//
#include <hip/hip_runtime.h>
#include <float.h>

#define L_TOK 65536
#define DIM   64
#define NCODE 1024

// ---------------------------------------------------------------------------
// Kernel A: per-code ||e||^2 (fp32), sequential-k chain (same as round 1).
// ---------------------------------------------------------------------------
__global__ __launch_bounds__(256) void esum_kernel(const float* __restrict__ emb,
                                                   float* __restrict__ esum) {
    int n = blockIdx.x * 256 + threadIdx.x;
    if (n >= NCODE) return;
    const float* e = emb + ((size_t)n << 6);
    float s = 0.f;
#pragma unroll
    for (int k = 0; k < DIM; ++k) s = fmaf(e[k], e[k], s);
    esum[n] = s;
}

// ---------------------------------------------------------------------------
// Kernel B: argmin. lane = token, code index WAVE-UNIFORM so embedding reads
// scalarize to s_load and the hot loop is pure v_fmac (SGPR src).
//   - block = 64 tokens, 4 waves each covering a 256-code quarter
//   - per wave: 4 codes in flight (4 independent sequential-k FMA chains)
//   - numerics identical to the passing round-1 kernel:
//       a   = sequential fmaf chain over k=0..63
//       zs  = sequential fmaf chain over k=0..63
//       d   = (zs + esum[c]) - 2*a
//     ascending-index strict '<' scan == np.argmin first-wins; cross-wave
//     combine uses explicit lowest-index tie-break.
// ---------------------------------------------------------------------------
__global__ __launch_bounds__(256) void argmin_kernel(const float* __restrict__ z,
                                                     const float* __restrict__ emb,
                                                     const float* __restrict__ esum,
                                                     float* __restrict__ idx_out) {
    const int lane  = threadIdx.x & 63;
    const int wid   = __builtin_amdgcn_readfirstlane(threadIdx.x >> 6);
    const int token = blockIdx.x * 64 + lane;

    // z row -> 64 VGPRs
    const float* zr = z + ((size_t)token << 6);
    float zreg[DIM];
#pragma unroll
    for (int i = 0; i < 16; ++i) {
        float4 v = ((const float4*)zr)[i];
        zreg[4*i+0] = v.x; zreg[4*i+1] = v.y;
        zreg[4*i+2] = v.z; zreg[4*i+3] = v.w;
    }

    float zs = 0.f;
#pragma unroll
    for (int k = 0; k < DIM; ++k) zs = fmaf(zreg[k], zreg[k], zs);

    float best = FLT_MAX;
    int   bi   = 0;
    const int cbase = wid * 256;   // wave-uniform

    for (int c0 = cbase; c0 < cbase + 256; c0 += 4) {
        const float* __restrict__ e0 = emb + ((size_t)(c0 + 0) << 6);
        const float* __restrict__ e1 = emb + ((size_t)(c0 + 1) << 6);
        const float* __restrict__ e2 = emb + ((size_t)(c0 + 2) << 6);
        const float* __restrict__ e3 = emb + ((size_t)(c0 + 3) << 6);
        float a0 = 0.f, a1 = 0.f, a2 = 0.f, a3 = 0.f;
#pragma unroll
        for (int k = 0; k < DIM; ++k) {
            float zk = zreg[k];
            a0 = fmaf(zk, e0[k], a0);
            a1 = fmaf(zk, e1[k], a1);
            a2 = fmaf(zk, e2[k], a2);
            a3 = fmaf(zk, e3[k], a3);
        }
        float t0 = zs + esum[c0 + 0];
        float t1 = zs + esum[c0 + 1];
        float t2 = zs + esum[c0 + 2];
        float t3 = zs + esum[c0 + 3];
        float d0 = t0 - 2.0f * a0;
        float d1 = t1 - 2.0f * a1;
        float d2 = t2 - 2.0f * a2;
        float d3 = t3 - 2.0f * a3;
        if (d0 < best) { best = d0; bi = c0 + 0; }
        if (d1 < best) { best = d1; bi = c0 + 1; }
        if (d2 < best) { best = d2; bi = c0 + 2; }
        if (d3 < best) { best = d3; bi = c0 + 3; }
    }

    __shared__ float sb[4][64];
    __shared__ int   si[4][64];
    sb[wid][lane] = best;
    si[wid][lane] = bi;
    __syncthreads();

    if (threadIdx.x < 64) {
        float b = sb[0][lane];
        int   i = si[0][lane];
#pragma unroll
        for (int w = 1; w < 4; ++w) {
            float ob = sb[w][lane];
            int   oi = si[w][lane];
            if (ob < b || (ob == b && oi < i)) { b = ob; i = oi; }
        }
        idx_out[token] = (float)i;
    }
}

// ---------------------------------------------------------------------------
// Kernel C: z_q_st + per-block f64 loss partials (unchanged from round 1).
// ---------------------------------------------------------------------------
__global__ __launch_bounds__(256) void output_kernel(const float* __restrict__ z,
                                                     const float* __restrict__ emb,
                                                     const float* __restrict__ idx_f,
                                                     float* __restrict__ zq_out,
                                                     double* __restrict__ partials) {
    int gid = blockIdx.x * 256 + threadIdx.x;
    int l = gid >> 6;
    int k = gid & 63;
    int idx = (int)idx_f[l];

    float zv = z[gid];
    float ev = emb[(idx << 6) + k];
    float t    = ev - zv;
    float outv = zv + t;
    zq_out[gid] = outv;

    float sq = t * t;

    __shared__ double red[256];
    red[threadIdx.x] = (double)sq;
    __syncthreads();
    for (int s = 128; s > 0; s >>= 1) {
        if (threadIdx.x < s) red[threadIdx.x] += red[threadIdx.x + s];
        __syncthreads();
    }
    if (threadIdx.x == 0) partials[blockIdx.x] = red[0];
}

// ---------------------------------------------------------------------------
// Kernel D: final deterministic reduction (unchanged from round 1).
// ---------------------------------------------------------------------------
__global__ __launch_bounds__(256) void loss_kernel(const double* __restrict__ partials,
                                                   float* __restrict__ loss_out) {
    __shared__ double red[256];
    int t = threadIdx.x;
    double s = 0.0;
    for (int i = 0; i < 64; ++i) s += partials[t * 64 + i];
    red[t] = s;
    __syncthreads();
    for (int st = 128; st > 0; st >>= 1) {
        if (t < st) red[t] += red[t + st];
        __syncthreads();
    }
    if (t == 0) {
        double m  = red[0] / (double)(L_TOK * DIM);
        float  mf = (float)m;
        loss_out[0] = 0.25f * mf + mf;
    }
}

extern "C" void kernel_launch(void* const* d_in, const int* in_sizes, int n_in,
                              void* d_out, int out_size, void* d_ws, size_t ws_size,
                              hipStream_t stream) {
    const float* z   = (const float*)d_in[0];
    const float* emb = (const float*)d_in[1];

    float* out   = (float*)d_out;
    float* zq    = out;                 // [0, 4194304)
    float* loss  = out + 4194304;       // [4194304]
    float* idxf  = out + 4194305;       // [4194305, 4259841)

    float*  esum     = (float*)d_ws;                          // 1024 f32
    double* partials = (double*)((char*)d_ws + 8192);         // 16384 f64

    esum_kernel  <<<4,     256, 0, stream>>>(emb, esum);
    argmin_kernel<<<1024,  256, 0, stream>>>(z, emb, esum, idxf);
    output_kernel<<<16384, 256, 0, stream>>>(z, emb, idxf, zq, partials);
    loss_kernel  <<<1,     256, 0, stream>>>(partials, loss);
}

// Round 3
// 184.175 us; speedup vs baseline: 5.1536x; 1.0034x over previous
//
#include <hip/hip_runtime.h>
#include <float.h>

#define L_TOK 65536
#define DIM   64
#define NCODE 1024

// ---------------------------------------------------------------------------
// Kernel A: per-code ||e||^2 (fp32), sequential-k chain.
// ---------------------------------------------------------------------------
__global__ __launch_bounds__(256) void esum_kernel(const float* __restrict__ emb,
                                                   float* __restrict__ esum) {
    int n = blockIdx.x * 256 + threadIdx.x;
    if (n >= NCODE) return;
    const float* e = emb + ((size_t)n << 6);
    float s = 0.f;
#pragma unroll
    for (int k = 0; k < DIM; ++k) s = fmaf(e[k], e[k], s);
    esum[n] = s;
}

// ---------------------------------------------------------------------------
// Kernel B: argmin. lane = token, code index wave-uniform -> embedding reads
// scalarize to s_load; hot loop = pure v_fmac(SGPR, VGPR).
// NEW vs round 2: z row PINNED into 64 VGPRs via empty asm so the compiler
// cannot rematerialize it with per-lane L1 loads inside the code loop
// (round-2 disasm evidence: VGPR_Count=44 => z was being re-loaded, creating
// an L1 VMEM path co-equal with VALU).
// Numerics identical to the passing kernels:
//   a  = sequential fmaf chain k=0..63, zs = sequential fmaf chain,
//   d  = (zs + esum[c]) - 2*a, ascending strict '<' scan, lowest-index ties.
// ---------------------------------------------------------------------------
__global__ __launch_bounds__(256) void argmin_kernel(const float* __restrict__ z,
                                                     const float* __restrict__ emb,
                                                     const float* __restrict__ esum,
                                                     float* __restrict__ idx_out) {
    const int lane  = threadIdx.x & 63;
    const int wid   = __builtin_amdgcn_readfirstlane(threadIdx.x >> 6);
    const int token = blockIdx.x * 64 + lane;

    const float* zr = z + ((size_t)token << 6);
    float zreg[DIM];
#pragma unroll
    for (int i = 0; i < 16; ++i) {
        float4 v = ((const float4*)zr)[i];
        zreg[4*i+0] = v.x; zreg[4*i+1] = v.y;
        zreg[4*i+2] = v.z; zreg[4*i+3] = v.w;
    }
    // Pin z into VGPRs: values become opaque -> no rematerialization/reload.
#pragma unroll
    for (int i = 0; i < DIM; ++i) {
        asm volatile("" : "+v"(zreg[i]));
    }

    float zs = 0.f;
#pragma unroll
    for (int k = 0; k < DIM; ++k) zs = fmaf(zreg[k], zreg[k], zs);

    float best = FLT_MAX;
    int   bi   = 0;
    const int cbase = wid * 256;   // wave-uniform

    for (int c0 = cbase; c0 < cbase + 256; c0 += 4) {
        const float* __restrict__ e0 = emb + ((size_t)(c0 + 0) << 6);
        const float* __restrict__ e1 = emb + ((size_t)(c0 + 1) << 6);
        const float* __restrict__ e2 = emb + ((size_t)(c0 + 2) << 6);
        const float* __restrict__ e3 = emb + ((size_t)(c0 + 3) << 6);
        float a0 = 0.f, a1 = 0.f, a2 = 0.f, a3 = 0.f;
#pragma unroll
        for (int k = 0; k < DIM; ++k) {
            float zk = zreg[k];
            a0 = fmaf(zk, e0[k], a0);
            a1 = fmaf(zk, e1[k], a1);
            a2 = fmaf(zk, e2[k], a2);
            a3 = fmaf(zk, e3[k], a3);
        }
        float t0 = zs + esum[c0 + 0];
        float t1 = zs + esum[c0 + 1];
        float t2 = zs + esum[c0 + 2];
        float t3 = zs + esum[c0 + 3];
        float d0 = t0 - 2.0f * a0;
        float d1 = t1 - 2.0f * a1;
        float d2 = t2 - 2.0f * a2;
        float d3 = t3 - 2.0f * a3;
        if (d0 < best) { best = d0; bi = c0 + 0; }
        if (d1 < best) { best = d1; bi = c0 + 1; }
        if (d2 < best) { best = d2; bi = c0 + 2; }
        if (d3 < best) { best = d3; bi = c0 + 3; }
    }

    __shared__ float sb[4][64];
    __shared__ int   si[4][64];
    sb[wid][lane] = best;
    si[wid][lane] = bi;
    __syncthreads();

    if (threadIdx.x < 64) {
        float b = sb[0][lane];
        int   i = si[0][lane];
#pragma unroll
        for (int w = 1; w < 4; ++w) {
            float ob = sb[w][lane];
            int   oi = si[w][lane];
            if (ob < b || (ob == b && oi < i)) { b = ob; i = oi; }
        }
        idx_out[token] = (float)i;
    }
}

// ---------------------------------------------------------------------------
// Kernel C: z_q_st + per-block f64 loss partials (unchanged).
// ---------------------------------------------------------------------------
__global__ __launch_bounds__(256) void output_kernel(const float* __restrict__ z,
                                                     const float* __restrict__ emb,
                                                     const float* __restrict__ idx_f,
                                                     float* __restrict__ zq_out,
                                                     double* __restrict__ partials) {
    int gid = blockIdx.x * 256 + threadIdx.x;
    int l = gid >> 6;
    int k = gid & 63;
    int idx = (int)idx_f[l];

    float zv = z[gid];
    float ev = emb[(idx << 6) + k];
    float t    = ev - zv;
    float outv = zv + t;
    zq_out[gid] = outv;

    float sq = t * t;

    __shared__ double red[256];
    red[threadIdx.x] = (double)sq;
    __syncthreads();
    for (int s = 128; s > 0; s >>= 1) {
        if (threadIdx.x < s) red[threadIdx.x] += red[threadIdx.x + s];
        __syncthreads();
    }
    if (threadIdx.x == 0) partials[blockIdx.x] = red[0];
}

// ---------------------------------------------------------------------------
// Kernel D: final deterministic reduction (unchanged).
// ---------------------------------------------------------------------------
__global__ __launch_bounds__(256) void loss_kernel(const double* __restrict__ partials,
                                                   float* __restrict__ loss_out) {
    __shared__ double red[256];
    int t = threadIdx.x;
    double s = 0.0;
    for (int i = 0; i < 64; ++i) s += partials[t * 64 + i];
    red[t] = s;
    __syncthreads();
    for (int st = 128; st > 0; st >>= 1) {
        if (t < st) red[t] += red[t + st];
        __syncthreads();
    }
    if (t == 0) {
        double m  = red[0] / (double)(L_TOK * DIM);
        float  mf = (float)m;
        loss_out[0] = 0.25f * mf + mf;
    }
}

extern "C" void kernel_launch(void* const* d_in, const int* in_sizes, int n_in,
                              void* d_out, int out_size, void* d_ws, size_t ws_size,
                              hipStream_t stream) {
    const float* z   = (const float*)d_in[0];
    const float* emb = (const float*)d_in[1];

    float* out   = (float*)d_out;
    float* zq    = out;                 // [0, 4194304)
    float* loss  = out + 4194304;       // [4194304]
    float* idxf  = out + 4194305;       // [4194305, 4259841)

    float*  esum     = (float*)d_ws;                          // 1024 f32
    double* partials = (double*)((char*)d_ws + 8192);         // 16384 f64

    esum_kernel  <<<4,     256, 0, stream>>>(emb, esum);
    argmin_kernel<<<1024,  256, 0, stream>>>(z, emb, esum, idxf);
    output_kernel<<<16384, 256, 0, stream>>>(z, emb, idxf, zq, partials);
    loss_kernel  <<<1,     256, 0, stream>>>(partials, loss);
}